// Round 6
// baseline (189.263 us; speedup 1.0000x reference)
//
#include <hip/hip_runtime.h>
#include <hip/hip_bf16.h>

// DepthLossWithMask: loss = sum(|output - label0| * label1) / count(label0 != 0)
// N = 16*15*256*256 = 15,728,640 floats -> n4 = 3,932,160 float4 = 7.5 * 524288.
//
// R5 finding: compiler collapsed every software pipeline (VGPR 52->28->20),
// leaving ~3 loads/wave in flight. R6: fully unrolled 8-iteration sweep with
// 4 rotating register buffers, prefetch distance 3, and sched_barrier(0)
// fences so the scheduler CANNOT sink loads into the consume. ~9 dwordx4
// per wave genuinely outstanding. Machine-observed streaming ceiling ~3.1 TB/s
// (harness restore copy speed); target stage1 ~59 us.

#define THREADS 256
#define BLOCKS  2048
#define SSTRIDE (BLOCKS * THREADS)   // 524288 float4 per sweep
#define ITERS   8                    // ceil(3932160 / 524288); 8th is half-populated
#define NBUF    4
#define DIST    3

struct Partial {
    float s;
    unsigned int c;
};

__device__ __forceinline__ void accum(const float4& o, const float4& a,
                                      const float4& w, float& sum,
                                      unsigned int& cnt) {
    sum += fabsf(o.x - a.x) * w.x;
    sum += fabsf(o.y - a.y) * w.y;
    sum += fabsf(o.z - a.z) * w.z;
    sum += fabsf(o.w - a.w) * w.w;
    cnt += (a.x != 0.0f) + (a.y != 0.0f) + (a.z != 0.0f) + (a.w != 0.0f);
}

__global__ __launch_bounds__(THREADS, 6)
void depth_loss_stage1(const float4* __restrict__ out,
                       const float4* __restrict__ l0,
                       const float4* __restrict__ l1,
                       Partial* __restrict__ partials,
                       int n4) {
    const int tid = blockIdx.x * THREADS + threadIdx.x;
    const int tail_n = n4 - (ITERS - 1) * SSTRIDE;   // 262144: threads below this do 8 iters

    float4 o[NBUF], a[NBUF], w[NBUF];

    // Prologue: iterations 0..DIST-1 (always in range: tid + 2*S < n4).
    #pragma unroll
    for (int k = 0; k < DIST; ++k) {
        int j = tid + k * SSTRIDE;
        o[k] = out[j];
        a[k] = l0[j];
        w[k] = l1[j];
    }

    float sum = 0.0f;
    unsigned int cnt = 0;

    #pragma unroll
    for (int k = 0; k < ITERS; ++k) {
        const int kp = k + DIST;
        if (kp < ITERS) {                       // constant-folded per unrolled k
            int j = tid + kp * SSTRIDE;
            if (kp == ITERS - 1) j = (tid < tail_n) ? j : tid;  // clamp tail load
            const int s = kp & (NBUF - 1);      // != k & (NBUF-1): no overwrite hazard
            o[s] = out[j];
            a[s] = l0[j];
            w[s] = l1[j];
        }
        // Hard fence: prefetch group must be fully issued before the consume;
        // scheduler may not sink these loads next to their (future) use.
        __builtin_amdgcn_sched_barrier(0);
        const int s = k & (NBUF - 1);
        if (k == ITERS - 1) {
            if (tid < tail_n) accum(o[s], a[s], w[s], sum, cnt);
        } else {
            accum(o[s], a[s], w[s], sum, cnt);
        }
    }

    // wave-64 butterfly reduce
    #pragma unroll
    for (int off = 32; off > 0; off >>= 1) {
        sum += __shfl_down(sum, off, 64);
        cnt += __shfl_down(cnt, off, 64);
    }

    __shared__ float        sv[THREADS / 64];
    __shared__ unsigned int sc[THREADS / 64];
    int lane = threadIdx.x & 63;
    int wid  = threadIdx.x >> 6;
    if (lane == 0) { sv[wid] = sum; sc[wid] = cnt; }
    __syncthreads();

    if (threadIdx.x == 0) {
        float bs = 0.0f;
        unsigned int bc = 0;
        #pragma unroll
        for (int k = 0; k < THREADS / 64; ++k) { bs += sv[k]; bc += sc[k]; }
        Partial p; p.s = bs; p.c = bc;
        partials[blockIdx.x] = p;   // plain 8B store, no contention
    }
}

__global__ __launch_bounds__(THREADS)
void depth_loss_stage2(const Partial* __restrict__ partials,
                       int nblocks,
                       float* __restrict__ out) {
    double sum = 0.0;
    unsigned int cnt = 0;
    for (int i = threadIdx.x; i < nblocks; i += THREADS) {
        Partial p = partials[i];
        sum += (double)p.s;
        cnt += p.c;
    }

    #pragma unroll
    for (int off = 32; off > 0; off >>= 1) {
        sum += __shfl_down(sum, off, 64);
        cnt += __shfl_down(cnt, off, 64);
    }

    __shared__ double       sv[THREADS / 64];
    __shared__ unsigned int sc[THREADS / 64];
    int lane = threadIdx.x & 63;
    int wid  = threadIdx.x >> 6;
    if (lane == 0) { sv[wid] = sum; sc[wid] = cnt; }
    __syncthreads();

    if (threadIdx.x == 0) {
        double bs = 0.0;
        unsigned int bc = 0;
        #pragma unroll
        for (int k = 0; k < THREADS / 64; ++k) { bs += sv[k]; bc += sc[k]; }
        out[0] = (bc == 0) ? 0.0f : (float)(bs / (double)bc);
    }
}

extern "C" void kernel_launch(void* const* d_in, const int* in_sizes, int n_in,
                              void* d_out, int out_size, void* d_ws, size_t ws_size,
                              hipStream_t stream) {
    const float* output = (const float*)d_in[0];
    const float* label0 = (const float*)d_in[1];
    const float* label1 = (const float*)d_in[2];
    int n = in_sizes[0];           // 15,728,640
    int n4 = n >> 2;               // 3,932,160 float4

    Partial* partials = (Partial*)d_ws;   // 2048*8 = 16 KB, every slot written

    depth_loss_stage1<<<BLOCKS, THREADS, 0, stream>>>(
        (const float4*)output, (const float4*)label0, (const float4*)label1,
        partials, n4);

    depth_loss_stage2<<<1, THREADS, 0, stream>>>(
        partials, BLOCKS, (float*)d_out);
}